// Round 4
// baseline (3613.134 us; speedup 1.0000x reference)
//
#include <hip/hip_runtime.h>
#include <hip/hip_bf16.h>
#include <hip/hip_cooperative_groups.h>

#define E   512
#define H   1024
#define BB  32
#define TT  512
#define G4  4096            // 4*H
#define NBLK 64             // recurrence blocks; each owns 16 h-columns
// d_out layout: ys [32][512][1024] fp32, then hn [32][1024], then cn [32][1024]
#define YS_ELEMS 16777216

typedef __attribute__((ext_vector_type(8))) short bf16x8;   // 8 bf16 in 4 VGPRs
typedef __attribute__((ext_vector_type(4))) float f32x4;

__device__ __forceinline__ unsigned short f2bf(float x){
    union { float f; unsigned u; } v; v.f = x;
    unsigned r = v.u + 0x7fffu + ((v.u >> 16) & 1u);   // RNE
    return (unsigned short)(r >> 16);
}
__device__ __forceinline__ float bf2f(unsigned short b){
    union { unsigned u; float f; } v; v.u = ((unsigned)b) << 16;
    return v.f;
}
__device__ __forceinline__ float sigm(float x){ return 1.f/(1.f+__expf(-x)); }
__device__ __forceinline__ float tanh_(float x){ return 2.f/(1.f+__expf(-2.f*x)) - 1.f; }

// ---------------- prep: gather+cast A, cast W_ih/W_hh/h0 to bf16; zero flags ----
__global__ void k_prep(const int* __restrict__ ids, const float* __restrict__ emb,
                       const float* __restrict__ Wih, const float* __restrict__ Whh,
                       const float* __restrict__ h0,
                       unsigned short* __restrict__ Abf, unsigned short* __restrict__ Bbf,
                       unsigned short* __restrict__ Wb,  unsigned short* __restrict__ hb,
                       unsigned* __restrict__ flags)
{
    int bx = blockIdx.x, tx = threadIdx.x;
    if (bx == 0) flags[tx] = 0;            // ws is poisoned 0xAA every launch; 256 flags
    const float* src; unsigned short* dst;
    if (bx < 4096) {                       // A gather: m = t*32+b, row = ids[b][t]
        unsigned u = bx*256u + tx;
        int m  = u >> 6;                   // 0..16383
        int e0 = (u & 63) * 8;             // 0..504
        int row = ids[(m & 31) * TT + (m >> 5)];
        src = emb + (size_t)row * E + e0;
        dst = Abf + (size_t)m   * E + e0;
    } else if (bx < 5120) {                // W_ih: 2,097,152 elems
        size_t off = ((size_t)(bx-4096)*256u + tx) * 8;
        src = Wih + off; dst = Bbf + off;
    } else if (bx < 7168) {                // W_hh: 4,194,304 elems
        size_t off = ((size_t)(bx-5120)*256u + tx) * 8;
        src = Whh + off; dst = Wb + off;
    } else {                               // h0: 32,768 elems
        size_t off = ((size_t)(bx-7168)*256u + tx) * 8;
        src = h0 + off; dst = hb + off;
    }
    float4 f0 = *(const float4*)(src);
    float4 f1 = *(const float4*)(src + 4);
    uint4 o;
    o.x = f2bf(f0.x) | ((unsigned)f2bf(f0.y) << 16);
    o.y = f2bf(f0.z) | ((unsigned)f2bf(f0.w) << 16);
    o.z = f2bf(f1.x) | ((unsigned)f2bf(f1.y) << 16);
    o.w = f2bf(f1.z) | ((unsigned)f2bf(f1.w) << 16);
    *(uint4*)dst = o;
}

// ---------------- x_proj GEMM: C[m][n] = sum_k A[m][k]*W_ih[n][k], bf16 out ------
__global__ __launch_bounds__(256) void k_gemm(const unsigned short* __restrict__ A,
        const unsigned short* __restrict__ Bm, unsigned short* __restrict__ C)
{
    __shared__ __align__(16) unsigned short As[128][40];
    __shared__ __align__(16) unsigned short Bs[128][40];
    int tid = threadIdx.x;
    int bm = blockIdx.x & 127;
    int bn = blockIdx.x >> 7;
    int w = tid >> 6, lane = tid & 63, l15 = lane & 15, quad = lane >> 4;
    int wm = w & 1, wn = w >> 1;
    f32x4 acc[4][4] = {};
    for (int kt = 0; kt < 16; ++kt) {
        __syncthreads();
        for (int i = 0; i < 2; ++i) {
            int c = tid + 256*i;
            int row = c >> 2, kc = (c & 3) * 8;
            *(uint4*)&As[row][kc] = *(const uint4*)(A  + ((size_t)(bm*128 + row))*E + kt*32 + kc);
            *(uint4*)&Bs[row][kc] = *(const uint4*)(Bm + ((size_t)(bn*128 + row))*E + kt*32 + kc);
        }
        __syncthreads();
        bf16x8 af[4], bfr[4];
        for (int i = 0; i < 4; ++i) af[i]  = *(const bf16x8*)&As[wm*64 + i*16 + l15][quad*8];
        for (int j = 0; j < 4; ++j) bfr[j] = *(const bf16x8*)&Bs[wn*64 + j*16 + l15][quad*8];
        for (int i = 0; i < 4; ++i)
            for (int j = 0; j < 4; ++j)
                acc[i][j] = __builtin_amdgcn_mfma_f32_16x16x32_bf16(af[i], bfr[j], acc[i][j], 0,0,0);
    }
    for (int i = 0; i < 4; ++i)
        for (int j = 0; j < 4; ++j)
            for (int r = 0; r < 4; ++r) {
                int mg = bm*128 + wm*64 + i*16 + quad*4 + r;
                int ng = bn*128 + wn*64 + j*16 + l15;
                C[(size_t)mg * G4 + ng] = f2bf(acc[i][j][r]);
            }
}

// ---------------- recurrence: 64 blocks x 512 thr (8 waves) --------------------
// Block blk owns h-columns blk*16..+15 (64 gate rows). Wave (nh=w>>2, kq=w&3):
// gates {nh*2, nh*2+1}, K-quarter kq*256. Weights: 16 bf16x8 = 64 VGPR/wave,
// loaded once (fits: peak ~150 regs). h(t) staged coalesced into LDS with the
// full 3-bit XOR swizzle (col ^ (row&7)<<4) -> conflict-free ds_read_b128.
// K-quarter partial gates reduced via gbuf[4][32][68] f32 in the epilogue.
// x_proj loads issued AFTER stage loads, waited with vmcnt(4) so they fly
// across ds_write/barrier/MFMA. Flag protocol identical to R1-R3 (proven).
__global__ __launch_bounds__(512, 1) void k_recur(const unsigned short* __restrict__ xp,
        const unsigned short* __restrict__ Wb, unsigned short* __restrict__ hbuf,
        const float* __restrict__ c0, float* __restrict__ out,
        unsigned* __restrict__ flags)
{
    __shared__ __align__(16) unsigned short Hs[BB*H];      // 64 KB, swizzled
    __shared__ __align__(16) float gbuf[4][32][68];        // [kq][b][n], 34.8 KB
    int tid = threadIdx.x;
    int blk = blockIdx.x;
    int w = tid >> 6, lane = tid & 63, l15 = lane & 15, quad = lane >> 4;
    int nh = w >> 2, kq = w & 3;

    // ---- W_hh preload: wave (nh,kq) -> gates nh*2, nh*2+1; rows blk*16+l15 ----
    bf16x8 wf0[8], wf1[8];
    {
        const unsigned short* wp0 = Wb + (size_t)((nh*2+0)*H + blk*16 + l15)*H + kq*256 + quad*8;
        const unsigned short* wp1 = wp0 + (size_t)H*H;
        #pragma unroll
        for (int k2 = 0; k2 < 8; ++k2) {
            wf0[k2] = *(const bf16x8*)(wp0 + k2*32);
            wf1[k2] = *(const bf16x8*)(wp1 + k2*32);
        }
    }
    // epilogue mapping (tid<256): wave w covers local cols w*4..w*4+3, 2/lane
    int b   = lane & 31;
    int kp  = lane >> 5;
    int cl0 = (w & 3)*4 + kp*2;
    int kg0 = blk*16 + cl0;
    float cA = 0.f, cB = 0.f;
    if (tid < 256) {
        float2 cc = *(const float2*)(c0 + b*H + kg0);
        cA = cc.x; cB = cc.y;
    }

    // ---- staging addresses: thread writes bytes i*8192 + tid*16, i=0..7 ----
    unsigned inrow = (unsigned)(tid & 127) * 16;
    unsigned rhi   = (unsigned)tid >> 7;                        // row&7 for even i
    char* dw_e = (char*)Hs + rhi*2048 + (inrow ^ (rhi << 4));   // i even
    char* dw_o = (char*)Hs + rhi*2048 + ((inrow ^ (rhi << 4)) ^ 64u); // i odd
    const char* g0 = (const char*)hbuf + (size_t)tid*16;
    const char* g1 = g0 + BB*H*2;

    // ---- A-fragment ds_read bases (swizzle folded) ----
    const char* hsb = (const char*)Hs;
    unsigned abase = (unsigned)kq*512u + (((unsigned)(l15 >> 2) & 1u)*64u)
                   + ((unsigned)(quad ^ (l15 & 3))*16u);
    const char* pe0 = hsb + l15*2048 + abase;        // rows 0..15, even k2
    const char* po0 = hsb + l15*2048 + (abase ^ 64u);
    const char* pe1 = pe0 + 16*2048;                 // rows 16..31
    const char* po1 = po0 + 16*2048;

    __syncthreads();

    for (int t = 0; t < TT; ++t) {
        // ---- barrier: wait until every block-wave has published h(t) ----
        if (tid < 64) {
            unsigned tgt = (unsigned)t;
            const unsigned* fp = flags + lane;
            bool ok;
            do {
                unsigned f0 = __hip_atomic_load(fp,       __ATOMIC_RELAXED, __HIP_MEMORY_SCOPE_AGENT);
                unsigned f1 = __hip_atomic_load(fp + 64,  __ATOMIC_RELAXED, __HIP_MEMORY_SCOPE_AGENT);
                unsigned f2 = __hip_atomic_load(fp + 128, __ATOMIC_RELAXED, __HIP_MEMORY_SCOPE_AGENT);
                unsigned f3 = __hip_atomic_load(fp + 192, __ATOMIC_RELAXED, __HIP_MEMORY_SCOPE_AGENT);
                ok = (f0 >= tgt) & (f1 >= tgt) & (f2 >= tgt) & (f3 >= tgt);
            } while (!__all(ok));
        }
        __syncthreads();
        // ---- stage h(t) coalesced; then x-prefetch rides behind (vmcnt(4)) ----
        const char* gsel = (t & 1) ? g1 : g0;
        uint4 s0,s1,s2,s3,s4,s5,s6,s7;
#define SLD(d,i) asm volatile("global_load_dwordx4 %0, %1, off sc0 sc1" \
                              : "=v"(d) : "v"(gsel + (size_t)(i)*8192))
        SLD(s0,0); SLD(s1,1); SLD(s2,2); SLD(s3,3);
        SLD(s4,4); SLD(s5,5); SLD(s6,6); SLD(s7,7);
#undef SLD
        unsigned xw0, xw1, xw2, xw3;
        if (tid < 256) {
            const char* xb0 = (const char*)(xp + ((size_t)t*BB + b)*G4 + kg0);
            const char* xb1 = xb0 + 4096;
            asm volatile("global_load_dword %0, %1, off"             : "=v"(xw0) : "v"(xb0));
            asm volatile("global_load_dword %0, %1, off offset:2048" : "=v"(xw1) : "v"(xb0));
            asm volatile("global_load_dword %0, %1, off"             : "=v"(xw2) : "v"(xb1));
            asm volatile("global_load_dword %0, %1, off offset:2048" : "=v"(xw3) : "v"(xb1));
            asm volatile("s_waitcnt vmcnt(4)" ::: "memory");   // stage done, x in flight
        } else {
            asm volatile("s_waitcnt vmcnt(0)" ::: "memory");
        }
        __builtin_amdgcn_sched_barrier(0);
        *(uint4*)(dw_e +     0) = s0;  *(uint4*)(dw_o +  8192) = s1;
        *(uint4*)(dw_e + 16384) = s2;  *(uint4*)(dw_o + 24576) = s3;
        *(uint4*)(dw_e + 32768) = s4;  *(uint4*)(dw_o + 40960) = s5;
        *(uint4*)(dw_e + 49152) = s6;  *(uint4*)(dw_o + 57344) = s7;
        __syncthreads();
        // ---- gates: wave (nh,kq): 2 gates x M32 x K256 = 32 MFMAs, 4 chains ----
        f32x4 a00 = {}, a01 = {}, a10 = {}, a11 = {};
        #pragma unroll
        for (int k2 = 0; k2 < 8; ++k2) {
            const char* q0 = (k2 & 1) ? po0 : pe0;
            const char* q1 = (k2 & 1) ? po1 : pe1;
            bf16x8 A0 = *(const bf16x8*)(q0 + (k2 >> 1)*128);
            bf16x8 A1 = *(const bf16x8*)(q1 + (k2 >> 1)*128);
            a00 = __builtin_amdgcn_mfma_f32_16x16x32_bf16(A0, wf0[k2], a00, 0,0,0);
            a10 = __builtin_amdgcn_mfma_f32_16x16x32_bf16(A1, wf0[k2], a10, 0,0,0);
            a01 = __builtin_amdgcn_mfma_f32_16x16x32_bf16(A0, wf1[k2], a01, 0,0,0);
            a11 = __builtin_amdgcn_mfma_f32_16x16x32_bf16(A1, wf1[k2], a11, 0,0,0);
        }
        {
            int n0 = nh*32 + l15, n1 = n0 + 16;
            #pragma unroll
            for (int r = 0; r < 4; ++r) {
                gbuf[kq][quad*4 + r][n0]      = a00[r];
                gbuf[kq][quad*4 + r][n1]      = a01[r];
                gbuf[kq][16 + quad*4 + r][n0] = a10[r];
                gbuf[kq][16 + quad*4 + r][n1] = a11[r];
            }
        }
        __syncthreads();
        // ---- epilogue: waves 0-3, 2 columns per lane (proven protocol) ----
        if (tid < 256) {
            asm volatile("s_waitcnt vmcnt(0)" ::: "memory");   // x loads done
            __builtin_amdgcn_sched_barrier(0);
            float xA[4], xB[4];
            xA[0] = bf2f((unsigned short)(xw0 & 0xffffu)); xB[0] = bf2f((unsigned short)(xw0 >> 16));
            xA[1] = bf2f((unsigned short)(xw1 & 0xffffu)); xB[1] = bf2f((unsigned short)(xw1 >> 16));
            xA[2] = bf2f((unsigned short)(xw2 & 0xffffu)); xB[2] = bf2f((unsigned short)(xw2 >> 16));
            xA[3] = bf2f((unsigned short)(xw3 & 0xffffu)); xB[3] = bf2f((unsigned short)(xw3 >> 16));
            float pA[4], pB[4];
            #pragma unroll
            for (int g = 0; g < 4; ++g) {
                float2 s = *(const float2*)&gbuf[0][b][g*16 + cl0];
                float2 u = *(const float2*)&gbuf[1][b][g*16 + cl0];
                float2 v = *(const float2*)&gbuf[2][b][g*16 + cl0];
                float2 z = *(const float2*)&gbuf[3][b][g*16 + cl0];
                pA[g] = ((s.x + u.x) + (v.x + z.x)) + xA[g];
                pB[g] = ((s.y + u.y) + (v.y + z.y)) + xB[g];
            }
            float iA = sigm(pA[0]), fA = sigm(pA[1]), gA = tanh_(pA[2]), oA = sigm(pA[3]);
            float iB = sigm(pB[0]), fB = sigm(pB[1]), gB = tanh_(pB[2]), oB = sigm(pB[3]);
            cA = fA * cA + iA * gA;
            cB = fB * cB + iB * gB;
            float hA = oA * tanh_(cA);
            float hB = oB * tanh_(cB);
            // 1) publish h(t+1) to the coherence point
            unsigned short* nxt = hbuf + ((t+1) & 1) * (BB*H);
            unsigned hp = (unsigned)f2bf(hA) | ((unsigned)f2bf(hB) << 16);
            __hip_atomic_store((unsigned*)(nxt + b*H + kg0), hp,
                               __ATOMIC_RELAXED, __HIP_MEMORY_SCOPE_AGENT);
            // 2) drain this wave's vmem (h stores included), then raise its flag
            asm volatile("s_waitcnt vmcnt(0)" ::: "memory");
            if (lane == 0)
                __hip_atomic_store(&flags[w*64 + blk], (unsigned)(t+1),
                                   __ATOMIC_RELAXED, __HIP_MEMORY_SCOPE_AGENT);
            // 3) off-critical-path output stores
            *(float2*)(out + (size_t)b*(TT*H) + (size_t)t*H + kg0) = make_float2(hA, hB);
            if (t == TT-1) {
                *(float2*)(out + YS_ELEMS + b*H + kg0)         = make_float2(hA, hB);
                *(float2*)(out + YS_ELEMS + 32768 + b*H + kg0) = make_float2(cA, cB);
            }
        }
    }
}

// ---------------- launch --------------------------------------------------------
extern "C" void kernel_launch(void* const* d_in, const int* in_sizes, int n_in,
                              void* d_out, int out_size, void* d_ws, size_t ws_size,
                              hipStream_t stream)
{
    const int*   ids = (const int*)  d_in[0];
    const float* h0  = (const float*)d_in[1];
    const float* c0  = (const float*)d_in[2];
    const float* emb = (const float*)d_in[3];
    const float* Wih = (const float*)d_in[4];
    const float* Whh = (const float*)d_in[5];
    float* out = (float*)d_out;
    char* ws = (char*)d_ws;
    unsigned short* xp  = (unsigned short*)(ws);                          // 134,217,728 B
    unsigned short* Abf = (unsigned short*)(ws + 134217728);              //  16,777,216 B
    unsigned short* Bbf = (unsigned short*)(ws + 134217728 + 16777216);   //   4,194,304 B
    unsigned short* Wb  = (unsigned short*)(ws + 134217728 + 16777216 + 4194304);          // 8,388,608 B
    unsigned short* hb  = (unsigned short*)(ws + 134217728 + 16777216 + 4194304 + 8388608); //  131,072 B
    unsigned*       fl  = (unsigned*)      (ws + 134217728 + 16777216 + 4194304 + 8388608 + 131072); // 1,024 B

    k_prep<<<7184, 256, 0, stream>>>(ids, emb, Wih, Whh, h0, Abf, Bbf, Wb, hb, fl);
    k_gemm<<<4096, 256, 0, stream>>>(Abf, Bbf, xp);
    void* args[] = { (void*)&xp, (void*)&Wb, (void*)&hb, (void*)&c0, (void*)&out, (void*)&fl };
    hipLaunchCooperativeKernel((void*)k_recur, dim3(NBLK), dim3(512), args, 0, stream);
}

// Round 5
// 3430.982 us; speedup vs baseline: 1.0531x; 1.0531x over previous
//
#include <hip/hip_runtime.h>
#include <hip/hip_bf16.h>
#include <hip/hip_cooperative_groups.h>

#define E   512
#define H   1024
#define BB  32
#define TT  512
#define G4  4096            // 4*H
#define NBLK 64             // recurrence blocks; each owns 16 h-columns
// d_out layout: ys [32][512][1024] fp32, then hn [32][1024], then cn [32][1024]
#define YS_ELEMS 16777216

typedef __attribute__((ext_vector_type(8))) short bf16x8;   // 8 bf16 in 4 VGPRs
typedef __attribute__((ext_vector_type(4))) float f32x4;

__device__ __forceinline__ unsigned short f2bf(float x){
    union { float f; unsigned u; } v; v.f = x;
    unsigned r = v.u + 0x7fffu + ((v.u >> 16) & 1u);   // RNE
    return (unsigned short)(r >> 16);
}
__device__ __forceinline__ float bf2f(unsigned short b){
    union { unsigned u; float f; } v; v.u = ((unsigned)b) << 16;
    return v.f;
}
__device__ __forceinline__ float sigm(float x){ return 1.f/(1.f+__expf(-x)); }
__device__ __forceinline__ float tanh_(float x){ return 2.f/(1.f+__expf(-2.f*x)) - 1.f; }

// ---------------- prep: gather+cast A, cast W_ih/W_hh/h0 to bf16; zero flags ----
__global__ void k_prep(const int* __restrict__ ids, const float* __restrict__ emb,
                       const float* __restrict__ Wih, const float* __restrict__ Whh,
                       const float* __restrict__ h0,
                       unsigned short* __restrict__ Abf, unsigned short* __restrict__ Bbf,
                       unsigned short* __restrict__ Wb,  unsigned short* __restrict__ hb,
                       unsigned* __restrict__ flags)
{
    int bx = blockIdx.x, tx = threadIdx.x;
    if (bx == 0) flags[tx] = 0;            // ws is poisoned 0xAA every launch; 256 flags
    const float* src; unsigned short* dst;
    if (bx < 4096) {                       // A gather: m = t*32+b, row = ids[b][t]
        unsigned u = bx*256u + tx;
        int m  = u >> 6;                   // 0..16383
        int e0 = (u & 63) * 8;             // 0..504
        int row = ids[(m & 31) * TT + (m >> 5)];
        src = emb + (size_t)row * E + e0;
        dst = Abf + (size_t)m   * E + e0;
    } else if (bx < 5120) {                // W_ih: 2,097,152 elems
        size_t off = ((size_t)(bx-4096)*256u + tx) * 8;
        src = Wih + off; dst = Bbf + off;
    } else if (bx < 7168) {                // W_hh: 4,194,304 elems
        size_t off = ((size_t)(bx-5120)*256u + tx) * 8;
        src = Whh + off; dst = Wb + off;
    } else {                               // h0: 32,768 elems
        size_t off = ((size_t)(bx-7168)*256u + tx) * 8;
        src = h0 + off; dst = hb + off;
    }
    float4 f0 = *(const float4*)(src);
    float4 f1 = *(const float4*)(src + 4);
    uint4 o;
    o.x = f2bf(f0.x) | ((unsigned)f2bf(f0.y) << 16);
    o.y = f2bf(f0.z) | ((unsigned)f2bf(f0.w) << 16);
    o.z = f2bf(f1.x) | ((unsigned)f2bf(f1.y) << 16);
    o.w = f2bf(f1.z) | ((unsigned)f2bf(f1.w) << 16);
    *(uint4*)dst = o;
}

// ---------------- x_proj GEMM: C[m][n] = sum_k A[m][k]*W_ih[n][k], bf16 out ------
__global__ __launch_bounds__(256) void k_gemm(const unsigned short* __restrict__ A,
        const unsigned short* __restrict__ Bm, unsigned short* __restrict__ C)
{
    __shared__ __align__(16) unsigned short As[128][40];
    __shared__ __align__(16) unsigned short Bs[128][40];
    int tid = threadIdx.x;
    int bm = blockIdx.x & 127;
    int bn = blockIdx.x >> 7;
    int w = tid >> 6, lane = tid & 63, l15 = lane & 15, quad = lane >> 4;
    int wm = w & 1, wn = w >> 1;
    f32x4 acc[4][4] = {};
    for (int kt = 0; kt < 16; ++kt) {
        __syncthreads();
        for (int i = 0; i < 2; ++i) {
            int c = tid + 256*i;
            int row = c >> 2, kc = (c & 3) * 8;
            *(uint4*)&As[row][kc] = *(const uint4*)(A  + ((size_t)(bm*128 + row))*E + kt*32 + kc);
            *(uint4*)&Bs[row][kc] = *(const uint4*)(Bm + ((size_t)(bn*128 + row))*E + kt*32 + kc);
        }
        __syncthreads();
        bf16x8 af[4], bfr[4];
        for (int i = 0; i < 4; ++i) af[i]  = *(const bf16x8*)&As[wm*64 + i*16 + l15][quad*8];
        for (int j = 0; j < 4; ++j) bfr[j] = *(const bf16x8*)&Bs[wn*64 + j*16 + l15][quad*8];
        for (int i = 0; i < 4; ++i)
            for (int j = 0; j < 4; ++j)
                acc[i][j] = __builtin_amdgcn_mfma_f32_16x16x32_bf16(af[i], bfr[j], acc[i][j], 0,0,0);
    }
    for (int i = 0; i < 4; ++i)
        for (int j = 0; j < 4; ++j)
            for (int r = 0; r < 4; ++r) {
                int mg = bm*128 + wm*64 + i*16 + quad*4 + r;
                int ng = bn*128 + wn*64 + j*16 + l15;
                C[(size_t)mg * G4 + ng] = f2bf(acc[i][j][r]);
            }
}

// ---------------- recurrence: 64 blocks x 512 thr (8 waves) --------------------
// Block blk owns h-columns blk*16..+15 (64 gate rows). Wave (nh=w>>2, kq=w&3):
// gates {nh*2, nh*2+1}, K-quarter kq*256. Weights: 16 bf16x8 = 64 VGPR/wave,
// loaded ONCE via asm volatile (non-rematerializable -> genuinely resident;
// R3/R4 used C++ loads and the compiler sank them back into the t-loop,
// re-streaming 128KB/block/step from L2 -- the validated failure mode).
// h(t) staged coalesced into LDS with the 3-bit XOR swizzle -> conflict-free
// ds_read_b128. K-quarter partials reduced via gbuf[4][32][66] (stride 66:
// bank stride 2 -> <=2-way, free; 8B-aligned float2 reads). x_proj loads
// issued after stage loads, waited with vmcnt(4). Flag protocol proven R1-R4.
__global__ __launch_bounds__(512, 1) void k_recur(const unsigned short* __restrict__ xp,
        const unsigned short* __restrict__ Wb, unsigned short* __restrict__ hbuf,
        const float* __restrict__ c0, float* __restrict__ out,
        unsigned* __restrict__ flags)
{
    __shared__ __align__(16) unsigned short Hs[BB*H];      // 64 KB, swizzled
    __shared__ __align__(16) float gbuf[4][32][66];        // [kq][b][n], 33.8 KB
    int tid = threadIdx.x;
    int blk = blockIdx.x;
    int w = tid >> 6, lane = tid & 63, l15 = lane & 15, quad = lane >> 4;
    int nh = w >> 2, kq = w & 3;

    // ---- W_hh preload: wave (nh,kq) -> gates nh*2, nh*2+1; rows blk*16+l15 ----
    // asm volatile pins these 64 VGPRs: cannot be rematerialized into the loop.
    bf16x8 wf0[8], wf1[8];
    {
        const unsigned short* wp0 = Wb + (size_t)((nh*2+0)*H + blk*16 + l15)*H + kq*256 + quad*8;
        const unsigned short* wp1 = wp0 + (size_t)H*H;
#define WLD(d, p, O) asm volatile("global_load_dwordx4 %0, %1, off offset:" O \
                                  : "=v"(d) : "v"(p))
        WLD(wf0[0], wp0, "0");   WLD(wf0[1], wp0, "64");
        WLD(wf0[2], wp0, "128"); WLD(wf0[3], wp0, "192");
        WLD(wf0[4], wp0, "256"); WLD(wf0[5], wp0, "320");
        WLD(wf0[6], wp0, "384"); WLD(wf0[7], wp0, "448");
        WLD(wf1[0], wp1, "0");   WLD(wf1[1], wp1, "64");
        WLD(wf1[2], wp1, "128"); WLD(wf1[3], wp1, "192");
        WLD(wf1[4], wp1, "256"); WLD(wf1[5], wp1, "320");
        WLD(wf1[6], wp1, "384"); WLD(wf1[7], wp1, "448");
#undef WLD
        asm volatile("s_waitcnt vmcnt(0)" ::: "memory");
        __builtin_amdgcn_sched_barrier(0);
    }
    // epilogue mapping (tid<256): wave w covers local cols w*4..w*4+3, 2/lane
    int b   = lane & 31;
    int kp  = lane >> 5;
    int cl0 = (w & 3)*4 + kp*2;
    int kg0 = blk*16 + cl0;
    float cA = 0.f, cB = 0.f;
    if (tid < 256) {
        float2 cc = *(const float2*)(c0 + b*H + kg0);
        cA = cc.x; cB = cc.y;
    }

    // ---- staging addresses: thread writes bytes i*8192 + tid*16, i=0..7 ----
    unsigned inrow = (unsigned)(tid & 127) * 16;
    unsigned rhi   = (unsigned)tid >> 7;                        // row&7 for even i
    char* dw_e = (char*)Hs + rhi*2048 + (inrow ^ (rhi << 4));   // i even
    char* dw_o = (char*)Hs + rhi*2048 + ((inrow ^ (rhi << 4)) ^ 64u); // i odd
    const char* g0 = (const char*)hbuf + (size_t)tid*16;
    const char* g1 = g0 + BB*H*2;

    // ---- A-fragment ds_read bases (swizzle folded) ----
    const char* hsb = (const char*)Hs;
    unsigned abase = (unsigned)kq*512u + (((unsigned)(l15 >> 2) & 1u)*64u)
                   + ((unsigned)(quad ^ (l15 & 3))*16u);
    const char* pe0 = hsb + l15*2048 + abase;        // rows 0..15, even k2
    const char* po0 = hsb + l15*2048 + (abase ^ 64u);
    const char* pe1 = pe0 + 16*2048;                 // rows 16..31
    const char* po1 = po0 + 16*2048;

    __syncthreads();

    for (int t = 0; t < TT; ++t) {
        // ---- barrier: wait until every block-wave has published h(t) ----
        if (tid < 64) {
            unsigned tgt = (unsigned)t;
            const unsigned* fp = flags + lane;
            bool ok;
            do {
                unsigned f0 = __hip_atomic_load(fp,       __ATOMIC_RELAXED, __HIP_MEMORY_SCOPE_AGENT);
                unsigned f1 = __hip_atomic_load(fp + 64,  __ATOMIC_RELAXED, __HIP_MEMORY_SCOPE_AGENT);
                unsigned f2 = __hip_atomic_load(fp + 128, __ATOMIC_RELAXED, __HIP_MEMORY_SCOPE_AGENT);
                unsigned f3 = __hip_atomic_load(fp + 192, __ATOMIC_RELAXED, __HIP_MEMORY_SCOPE_AGENT);
                ok = (f0 >= tgt) & (f1 >= tgt) & (f2 >= tgt) & (f3 >= tgt);
            } while (!__all(ok));
        }
        __syncthreads();
        // ---- stage h(t) coalesced; then x-prefetch rides behind (vmcnt(4)) ----
        const char* gsel = (t & 1) ? g1 : g0;
        uint4 s0,s1,s2,s3,s4,s5,s6,s7;
#define SLD(d,i) asm volatile("global_load_dwordx4 %0, %1, off sc0 sc1" \
                              : "=v"(d) : "v"(gsel + (size_t)(i)*8192))
        SLD(s0,0); SLD(s1,1); SLD(s2,2); SLD(s3,3);
        SLD(s4,4); SLD(s5,5); SLD(s6,6); SLD(s7,7);
#undef SLD
        unsigned xw0, xw1, xw2, xw3;
        if (tid < 256) {
            const char* xb0 = (const char*)(xp + ((size_t)t*BB + b)*G4 + kg0);
            const char* xb1 = xb0 + 4096;
            asm volatile("global_load_dword %0, %1, off"             : "=v"(xw0) : "v"(xb0));
            asm volatile("global_load_dword %0, %1, off offset:2048" : "=v"(xw1) : "v"(xb0));
            asm volatile("global_load_dword %0, %1, off"             : "=v"(xw2) : "v"(xb1));
            asm volatile("global_load_dword %0, %1, off offset:2048" : "=v"(xw3) : "v"(xb1));
            asm volatile("s_waitcnt vmcnt(4)" ::: "memory");   // stage done, x in flight
        } else {
            asm volatile("s_waitcnt vmcnt(0)" ::: "memory");
        }
        __builtin_amdgcn_sched_barrier(0);
        *(uint4*)(dw_e +     0) = s0;  *(uint4*)(dw_o +  8192) = s1;
        *(uint4*)(dw_e + 16384) = s2;  *(uint4*)(dw_o + 24576) = s3;
        *(uint4*)(dw_e + 32768) = s4;  *(uint4*)(dw_o + 40960) = s5;
        *(uint4*)(dw_e + 49152) = s6;  *(uint4*)(dw_o + 57344) = s7;
        __syncthreads();
        // ---- gates: wave (nh,kq): 2 gates x M32 x K256 = 32 MFMAs, 4 chains ----
        f32x4 a00 = {}, a01 = {}, a10 = {}, a11 = {};
        #pragma unroll
        for (int k2 = 0; k2 < 8; ++k2) {
            const char* q0 = (k2 & 1) ? po0 : pe0;
            const char* q1 = (k2 & 1) ? po1 : pe1;
            bf16x8 A0 = *(const bf16x8*)(q0 + (k2 >> 1)*128);
            bf16x8 A1 = *(const bf16x8*)(q1 + (k2 >> 1)*128);
            a00 = __builtin_amdgcn_mfma_f32_16x16x32_bf16(A0, wf0[k2], a00, 0,0,0);
            a10 = __builtin_amdgcn_mfma_f32_16x16x32_bf16(A1, wf0[k2], a10, 0,0,0);
            a01 = __builtin_amdgcn_mfma_f32_16x16x32_bf16(A0, wf1[k2], a01, 0,0,0);
            a11 = __builtin_amdgcn_mfma_f32_16x16x32_bf16(A1, wf1[k2], a11, 0,0,0);
        }
        {
            int n0 = nh*32 + l15, n1 = n0 + 16;
            #pragma unroll
            for (int r = 0; r < 4; ++r) {
                gbuf[kq][quad*4 + r][n0]      = a00[r];
                gbuf[kq][quad*4 + r][n1]      = a01[r];
                gbuf[kq][16 + quad*4 + r][n0] = a10[r];
                gbuf[kq][16 + quad*4 + r][n1] = a11[r];
            }
        }
        __syncthreads();
        // ---- epilogue: waves 0-3, 2 columns per lane (proven protocol) ----
        if (tid < 256) {
            asm volatile("s_waitcnt vmcnt(0)" ::: "memory");   // x loads done
            __builtin_amdgcn_sched_barrier(0);
            float xA[4], xB[4];
            xA[0] = bf2f((unsigned short)(xw0 & 0xffffu)); xB[0] = bf2f((unsigned short)(xw0 >> 16));
            xA[1] = bf2f((unsigned short)(xw1 & 0xffffu)); xB[1] = bf2f((unsigned short)(xw1 >> 16));
            xA[2] = bf2f((unsigned short)(xw2 & 0xffffu)); xB[2] = bf2f((unsigned short)(xw2 >> 16));
            xA[3] = bf2f((unsigned short)(xw3 & 0xffffu)); xB[3] = bf2f((unsigned short)(xw3 >> 16));
            float pA[4], pB[4];
            #pragma unroll
            for (int g = 0; g < 4; ++g) {
                float2 s = *(const float2*)&gbuf[0][b][g*16 + cl0];
                float2 u = *(const float2*)&gbuf[1][b][g*16 + cl0];
                float2 v = *(const float2*)&gbuf[2][b][g*16 + cl0];
                float2 z = *(const float2*)&gbuf[3][b][g*16 + cl0];
                pA[g] = ((s.x + u.x) + (v.x + z.x)) + xA[g];
                pB[g] = ((s.y + u.y) + (v.y + z.y)) + xB[g];
            }
            float iA = sigm(pA[0]), fA = sigm(pA[1]), gA = tanh_(pA[2]), oA = sigm(pA[3]);
            float iB = sigm(pB[0]), fB = sigm(pB[1]), gB = tanh_(pB[2]), oB = sigm(pB[3]);
            cA = fA * cA + iA * gA;
            cB = fB * cB + iB * gB;
            float hA = oA * tanh_(cA);
            float hB = oB * tanh_(cB);
            // 1) publish h(t+1) to the coherence point
            unsigned short* nxt = hbuf + ((t+1) & 1) * (BB*H);
            unsigned hp = (unsigned)f2bf(hA) | ((unsigned)f2bf(hB) << 16);
            __hip_atomic_store((unsigned*)(nxt + b*H + kg0), hp,
                               __ATOMIC_RELAXED, __HIP_MEMORY_SCOPE_AGENT);
            // 2) drain this wave's vmem (h stores included), then raise its flag
            asm volatile("s_waitcnt vmcnt(0)" ::: "memory");
            if (lane == 0)
                __hip_atomic_store(&flags[w*64 + blk], (unsigned)(t+1),
                                   __ATOMIC_RELAXED, __HIP_MEMORY_SCOPE_AGENT);
            // 3) off-critical-path output stores
            *(float2*)(out + (size_t)b*(TT*H) + (size_t)t*H + kg0) = make_float2(hA, hB);
            if (t == TT-1) {
                *(float2*)(out + YS_ELEMS + b*H + kg0)         = make_float2(hA, hB);
                *(float2*)(out + YS_ELEMS + 32768 + b*H + kg0) = make_float2(cA, cB);
            }
        }
    }
}

// ---------------- launch --------------------------------------------------------
extern "C" void kernel_launch(void* const* d_in, const int* in_sizes, int n_in,
                              void* d_out, int out_size, void* d_ws, size_t ws_size,
                              hipStream_t stream)
{
    const int*   ids = (const int*)  d_in[0];
    const float* h0  = (const float*)d_in[1];
    const float* c0  = (const float*)d_in[2];
    const float* emb = (const float*)d_in[3];
    const float* Wih = (const float*)d_in[4];
    const float* Whh = (const float*)d_in[5];
    float* out = (float*)d_out;
    char* ws = (char*)d_ws;
    unsigned short* xp  = (unsigned short*)(ws);                          // 134,217,728 B
    unsigned short* Abf = (unsigned short*)(ws + 134217728);              //  16,777,216 B
    unsigned short* Bbf = (unsigned short*)(ws + 134217728 + 16777216);   //   4,194,304 B
    unsigned short* Wb  = (unsigned short*)(ws + 134217728 + 16777216 + 4194304);          // 8,388,608 B
    unsigned short* hb  = (unsigned short*)(ws + 134217728 + 16777216 + 4194304 + 8388608); //  131,072 B
    unsigned*       fl  = (unsigned*)      (ws + 134217728 + 16777216 + 4194304 + 8388608 + 131072); // 1,024 B

    k_prep<<<7184, 256, 0, stream>>>(ids, emb, Wih, Whh, h0, Abf, Bbf, Wb, hb, fl);
    k_gemm<<<4096, 256, 0, stream>>>(Abf, Bbf, xp);
    void* args[] = { (void*)&xp, (void*)&Wb, (void*)&hb, (void*)&c0, (void*)&out, (void*)&fl };
    hipLaunchCooperativeKernel((void*)k_recur, dim3(NBLK), dim3(512), args, 0, stream);
}